// Round 14
// baseline (818.263 us; speedup 1.0000x reference)
//
#include <hip/hip_runtime.h>
#include <math.h>

#define B_ 128
#define L_ 30
#define M_ 10
#define H_ 256
#define VN_ 32000
#define NCHK 500     // vocab chunks of 64 cols
#define NG 3712      // 29*128 rows

typedef __bf16 bf16;
typedef bf16 bf16x8 __attribute__((ext_vector_type(8)));
typedef float f32x4 __attribute__((ext_vector_type(4)));
typedef float f32x2 __attribute__((ext_vector_type(2)));

#define MFMA(a,b,c) __builtin_amdgcn_mfma_f32_16x16x32_bf16(a, b, c, 0, 0, 0)

__device__ __forceinline__ float rcpf(float x) { return __builtin_amdgcn_rcpf(x); }
__device__ __forceinline__ float sigf(float x) { return rcpf(1.f + __expf(-x)); }
__device__ __forceinline__ float ftanh(float x) {
  float e = __expf(2.f * x);
  return 1.f - 2.f * rcpf(e + 1.f);
}
__device__ __forceinline__ float u2lo(unsigned w) { return __builtin_bit_cast(float, w << 16); }
__device__ __forceinline__ float u2hi(unsigned w) { return __builtin_bit_cast(float, w & 0xffff0000u); }
__device__ __forceinline__ unsigned packbf2(float a, float b) {
  unsigned short lo = __builtin_bit_cast(unsigned short, (bf16)a);
  unsigned short hi = __builtin_bit_cast(unsigned short, (bf16)b);
  return (unsigned)lo | ((unsigned)hi << 16);
}

#if __has_builtin(__builtin_amdgcn_fdot2_f32_bf16)
typedef __bf16 bf16x2 __attribute__((ext_vector_type(2)));
__device__ __forceinline__ float dot2(unsigned x, unsigned w, float c) {
  return __builtin_amdgcn_fdot2_f32_bf16(__builtin_bit_cast(bf16x2, x),
                                         __builtin_bit_cast(bf16x2, w), c, false);
}
#else
__device__ __forceinline__ float dot2(unsigned x, unsigned w, float c) {
  c = fmaf(u2lo(x), u2lo(w), c);
  return fmaf(u2hi(x), u2hi(w), c);
}
#endif

// ---------------- fp8 e4m3 pack/unpack (HW cvt on gfx950, SW fallback) ----------------
// NOTE: the `hi` word-select of the cvt builtins is an instruction modifier and
// must be a compile-time constant -> template parameter.
#if __has_builtin(__builtin_amdgcn_cvt_pk_f32_fp8) && __has_builtin(__builtin_amdgcn_cvt_pk_fp8_f32)
template <bool HI>
__device__ __forceinline__ f32x2 upk8(unsigned u) {
  return __builtin_amdgcn_cvt_pk_f32_fp8((int)u, HI);
}
__device__ __forceinline__ unsigned pk8x4(float a, float b, float c, float d) {
  int v = __builtin_amdgcn_cvt_pk_fp8_f32(a, b, 0, false);
  v = __builtin_amdgcn_cvt_pk_fp8_f32(c, d, v, true);
  return (unsigned)v;
}
#else
__device__ __forceinline__ float dec8(unsigned byte) {
  unsigned s = byte >> 7, e = (byte >> 3) & 15, m = byte & 7;
  float v;
  if (e == 0) v = (float)m * __builtin_bit_cast(float, (unsigned)((-9 + 127) << 23));
  else        v = (float)(8 + m) * __builtin_bit_cast(float, (unsigned)(((int)e - 10 + 127) << 23));
  return s ? -v : v;
}
template <bool HI>
__device__ __forceinline__ f32x2 upk8(unsigned u) {
  unsigned sh = HI ? 16u : 0u;
  f32x2 r;
  r.x = dec8((u >> sh) & 0xff);
  r.y = dec8((u >> (sh + 8)) & 0xff);
  return r;
}
__device__ __forceinline__ unsigned enc8(float f) {
  if (f == 0.f || f != f) return 0;
  unsigned b = __builtin_bit_cast(unsigned, f);
  unsigned s = (b >> 31) << 7;
  int e = (int)((b >> 23) & 255) - 127;
  unsigned frac = b & 0x7fffff;
  if (e < -6) {
    float av = fabsf(f);
    int m = (int)(av * 512.f + 0.5f);
    if (m >= 8) return s | (1u << 3);
    return s | (unsigned)m;
  }
  int m = (int)((frac + 0x80000u) >> 20);
  int ee = e + 7;
  if (m == 8) { m = 0; ee++; }
  if (ee >= 16) { ee = 15; m = 6; }
  return s | ((unsigned)ee << 3) | (unsigned)m;
}
__device__ __forceinline__ unsigned pk8x4(float a, float b, float c, float d) {
  return enc8(a) | (enc8(b) << 8) | (enc8(c) << 16) | (enc8(d) << 24);
}
#endif

// fp8 uint2 (8 weights) dot against two bf16-pair x-words
__device__ __forceinline__ void dot8fp8(uint2 w, unsigned x,
                                        float& p0, float& p1, float& p2, float& p3) {
  float xl = u2lo(x), xh = u2hi(x);
  f32x2 c0 = upk8<false>(w.x), c1 = upk8<true>(w.x);
  f32x2 c2 = upk8<false>(w.y), c3 = upk8<true>(w.y);
  p0 = fmaf(xl, c0.x, fmaf(xh, c0.y, p0));
  p1 = fmaf(xl, c1.x, fmaf(xh, c1.y, p1));
  p2 = fmaf(xl, c2.x, fmaf(xh, c2.y, p2));
  p3 = fmaf(xl, c3.x, fmaf(xh, c3.y, p3));
}

// ---------------------------------------------------------------- weight prep (+ fused pregates, blocks >= 512)
__global__ __launch_bounds__(256) void k_prep(
    const float* W_ct, const float* W_hh,
    const float* W_n, const float* W_k, const float* W_v,
    const float* W_hn, const float* W_hk, const float* W_hv,
    const float* W_mk, const float* W_mv, const float* W_g,
    uint2* W8g, uint2* W8nkv, uint2* W8ph, unsigned* WctP45,
    unsigned* W4m0, unsigned* W4qm, unsigned* W4da, unsigned* W4db, unsigned* WgP,
    const int* sentence, const float* emb, const float* W_ih,
    const float* b_ih, const float* b_hh, float* prehg) {
  if (blockIdx.x >= 512) {
    // ======== pregates: emb@W_ih via MFMA (29 x 8 blocks) ========
    extern __shared__ char smp[];
    char* Al = smp;
    char* Bl = smp + 65536;
    __shared__ int tok_s[128];
    int blk = blockIdx.x - 512;
    int gd = blk >> 3, nc = blk & 7;
    int t = threadIdx.x, wid = t >> 6, lane = t & 63;
    if (t < 128) tok_s[t] = sentence[t*L_ + gd];
    __syncthreads();
    for (int i = t; i < 128*32; i += 256) {
      int r = i >> 5, c8 = i & 31;
      const float* e = emb + (size_t)tok_s[r]*H_ + c8*8;
      float4 f0 = *(const float4*)e, f1 = *(const float4*)(e + 4);
      int4 v;
      v.x = (int)packbf2(f0.x, f0.y); v.y = (int)packbf2(f0.z, f0.w);
      v.z = (int)packbf2(f1.x, f1.y); v.w = (int)packbf2(f1.z, f1.w);
      *(int4*)(Al + ((r*512 + c8*16) ^ ((r&7)<<4))) = v;
      const float* wsrc = W_ih + (size_t)(nc*128 + r)*H_ + c8*8;
      float4 g0 = *(const float4*)wsrc, g1 = *(const float4*)(wsrc + 4);
      int4 w;
      w.x = (int)packbf2(g0.x, g0.y); w.y = (int)packbf2(g0.z, g0.w);
      w.z = (int)packbf2(g1.x, g1.y); w.w = (int)packbf2(g1.z, g1.w);
      *(int4*)(Bl + ((r*512 + c8*16) ^ ((r&7)<<4))) = w;
    }
    __syncthreads();
    f32x4 acc[2][8] = {};
    #pragma unroll 2
    for (int kk = 0; kk < 8; ++kk) {
      int kb2 = kk*64 + (lane>>4)*16;
      bf16x8 af[2], bfr[8];
      #pragma unroll
      for (int fi = 0; fi < 2; ++fi) {
        int m = wid*32 + fi*16 + (lane & 15);
        af[fi] = *(const bf16x8*)(Al + ((m*512 + kb2) ^ ((m&7)<<4)));
      }
      #pragma unroll
      for (int fj = 0; fj < 8; ++fj) {
        int n = fj*16 + (lane & 15);
        bfr[fj] = *(const bf16x8*)(Bl + ((n*512 + kb2) ^ ((n&7)<<4)));
      }
      #pragma unroll
      for (int fi = 0; fi < 2; ++fi)
        #pragma unroll
        for (int fj = 0; fj < 8; ++fj)
          acc[fi][fj] = MFMA(af[fi], bfr[fj], acc[fi][fj]);
    }
    #pragma unroll
    for (int fi = 0; fi < 2; ++fi)
      #pragma unroll
      for (int fj = 0; fj < 8; ++fj)
        #pragma unroll
        for (int r = 0; r < 4; ++r) {
          int row = wid*32 + fi*16 + (lane>>4)*4 + r;
          int col = nc*128 + fj*16 + (lane & 15);
          prehg[((size_t)gd*128 + row)*1024 + col] = acc[fi][fj][r] + b_ih[col] + b_hh[col];
        }
    return;
  }
  int stride = 512 * blockDim.x;
  int base = blockIdx.x * blockDim.x + threadIdx.x;
  // W8g: uint2[i 32][t 1024] fp8: s0|s1 in .x, s2|s3 in .y; n=4*(t>>2)+s, k2=(t&3)+4*i
  for (int idx = base; idx < 32768; idx += stride) {
    int t = idx & 1023, i = idx >> 10;
    int nb = 4*(t >> 2), k2 = (t & 3) + 4*i;
    const float* w0 = W_hh + (size_t)nb*256 + 2*k2;
    uint2 o;
    o.x = pk8x4(w0[0], w0[1], w0[256], w0[257]);
    o.y = pk8x4(w0[512], w0[513], w0[768], w0[769]);
    W8g[idx] = o;
  }
  // W8nkv: uint2[i 32][t 768]: n=4*(t>>2)+s, k2=(t&3)+4*i
  for (int idx = base; idx < 24576; idx += stride) {
    int tt = idx % 768, i = idx / 768;
    int nb = 4*(tt >> 2), k2 = (tt & 3) + 4*i;
    float v[8];
    #pragma unroll
    for (int s = 0; s < 4; ++s) {
      int n = nb + s;
      const float* src = (n < 256) ? W_n : (n < 512) ? W_k : W_v;
      int nn = n & 255;
      v[2*s] = src[nn*256 + 2*k2]; v[2*s+1] = src[nn*256 + 2*k2 + 1];
    }
    uint2 o;
    o.x = pk8x4(v[0], v[1], v[2], v[3]);
    o.y = pk8x4(v[4], v[5], v[6], v[7]);
    W8nkv[idx] = o;
  }
  // W8ph: uint2[i 32][q 768]: X=q>>8, rr=q&255, ob=rr>>2, kq=rr&3; nl=4*ob+s, k2=kq+4*i
  for (int idx = base; idx < 24576; idx += stride) {
    int q = idx % 768, i = idx / 768;
    int X = q >> 8, rr = q & 255, ob = rr >> 2, kq = rr & 3;
    int k2 = kq + 4*i, col = X*256 + 2*k2;
    const float* w0 = W_ct + (size_t)(4*ob)*1280 + col;
    uint2 o;
    o.x = pk8x4(w0[0], w0[1], w0[1280], w0[1281]);
    o.y = pk8x4(w0[2560], w0[2561], w0[3840], w0[3841]);
    W8ph[idx] = o;
  }
  // WctP45 (init-only, bf16 [X 2][k2 128][n 256])
  for (int i = base; i < 65536; i += stride) {
    int X = i >> 15, r = i & 32767, k2 = r >> 8, n = r & 255;
    int col = 768 + X*256 + 2*k2;
    WctP45[i] = packbf2(W_ct[n*1280 + col], W_ct[n*1280 + col + 1]);
  }
  // W4m0: [i 32][t 32][s 4] bf16
  for (int idx = base; idx < 4096; idx += stride) {
    int s = idx & 3, tt = (idx >> 2) & 31, i = idx >> 7;
    int c = 4*(tt >> 2) + s, k2 = (tt & 3) + 4*i;
    float x0 = 0.f, x1 = 0.f;
    if (c < 10)              { x0 = W_mk[c*1024 + 2*k2]; x1 = W_mk[c*1024 + 2*k2 + 1]; }
    else if (c >= 16 && c < 26) { int m = c-16; x0 = W_mv[m*1024 + 2*k2]; x1 = W_mv[m*1024 + 2*k2 + 1]; }
    W4m0[idx] = packbf2(x0, x1);
  }
  // W4qm: [i 32][q 96][s 4] bf16
  for (int idx = base; idx < 12288; idx += stride) {
    int s = idx & 3, r2 = idx >> 2, q = r2 % 96, i = r2 / 96;
    int X = q >> 5, r = q & 31;
    int c = 4*(r >> 2) + s, k2 = (r & 3) + 4*i;
    int off = 256 + X*256 + 2*k2;
    float x0 = 0.f, x1 = 0.f;
    if (c < 10)              { x0 = W_mk[c*1024 + off]; x1 = W_mk[c*1024 + off + 1]; }
    else if (c >= 16 && c < 26) { int m = c-16; x0 = W_mv[m*1024 + off]; x1 = W_mv[m*1024 + off + 1]; }
    W4qm[idx] = packbf2(x0, x1);
  }
  // W4da: [d 30][i 32][t 128][s 4] bf16
  for (int idx = base; idx < 491520; idx += stride) {
    int s = idx & 3, tt = (idx >> 2) & 127, i = (idx >> 9) & 31, d = idx >> 14;
    int c = 4*(tt >> 2) + s, k2 = (tt & 3) + 4*i;
    float x0 = 0.f, x1 = 0.f;
    if (c < 96) {
      int X = c >> 5, l = c & 31;
      if (l < 30) {
        const float* W = (X == 0) ? W_hn : (X == 1) ? W_hk : W_hv;
        x0 = W[l*7936 + d*256 + 2*k2]; x1 = W[l*7936 + d*256 + 2*k2 + 1];
      }
    }
    W4da[idx] = packbf2(x0, x1);
  }
  // W4db: [i 32][t 128][s 4] bf16
  for (int idx = base; idx < 16384; idx += stride) {
    int s = idx & 3, tt = (idx >> 2) & 127, i = idx >> 9;
    int c = 4*(tt >> 2) + s, k2 = (tt & 3) + 4*i;
    float x0 = 0.f, x1 = 0.f;
    if (c < 96) {
      int X = c >> 5, l = c & 31;
      if (l < 30) {
        const float* W = (X == 0) ? W_hn : (X == 1) ? W_hk : W_hv;
        x0 = W[l*7936 + 2*k2]; x1 = W[l*7936 + 2*k2 + 1];
      }
    }
    W4db[idx] = packbf2(x0, x1);
  }
  for (int i = base; i < 128; i += stride) WgP[i] = packbf2(W_g[2*i], W_g[2*i+1]);
}

// ---------------------------------------------------------------- recurrence
struct LoopP {
  const int *sentence, *keywords, *categories, *memsz;
  const float *emb;
  const uint2 *W8g, *W8nkv, *W8ph;
  const unsigned *WctP45, *W4m0, *W4qm, *W4da, *W4db, *WgP;
  const float *prehg;
  const float *b_ct, *b_hn, *b_hk, *b_hv, *b_mk, *b_mv, *b_g;
  unsigned* hNb;
  unsigned* hNbT;
  float* gt_all;
  float* outg;
};

__global__ __launch_bounds__(1024) void k_loop(LoopP p) {
  extern __shared__ unsigned Su[];
  float* Sf = (float*)Su;
  const int t = threadIdx.x, b = blockIdx.x;
  enum { PH = 0, QM = 11520, P45 = 14400, MB = 16960,
         GA = 19520, HP = 20544, HV = 20672,
         SW = 21056, ACA = 21152, SWM = 21248, M0 = 21280,
         DA = 21312, DB = 21440,
         BCT = 21568, BH = 21824, BM = 21920, BG = 21952 };

  // ===== init =====
  for (int i = t; i < 2560; i += 1024) {
    int X = i / 1280, r = i - X*1280, m = r >> 7, j = r & 127;
    int ms = p.memsz[b];
    int idx = (X == 0 ? p.keywords : p.categories)[b*M_ + m];
    unsigned u = 0;
    if (m < ms) {
      const float* e = p.emb + (size_t)idx*H_ + 2*j;
      u = packbf2(e[0], e[1]);
    }
    Su[MB + i] = u;
  }
  if (t < 256) Sf[BCT + t] = p.b_ct[t];
  if (t < 96) {
    int X = t >> 5, l = t & 31;
    const float* bh = (X == 0) ? p.b_hn : (X == 1) ? p.b_hk : p.b_hv;
    Sf[BH + t] = (l < 30) ? bh[l] : 0.f;
    Sf[ACA + t] = 0.f;
  }
  if (t < 32) {
    float v = 0.f;
    if (t < 10) v = p.b_mk[t];
    else if (t >= 16 && t < 26) v = p.b_mv[t - 16];
    Sf[BM + t] = v;
  }
  if (t == 0) { Sf[BG] = p.b_g[0]; p.outg[b*L_] = 0.f; }
  __syncthreads();
  if (t < 128) {
    float a0 = 0.f, a1 = 0.f;
    #pragma unroll
    for (int q = 0; q < 20; ++q) {
      unsigned u = Su[MB + q*128 + t];
      a0 += u2lo(u); a1 += u2hi(u);
    }
    float msf = (float)p.memsz[b];
    unsigned up = packbf2(a0 / (2.f * msf), a1 / (2.f * msf));
    Su[HP + t] = up;
    Su[HV + t] = up; Su[HV + 128 + t] = up; Su[HV + 256 + t] = up;
  }
  for (int q = t; q < 2560; q += 1024) {
    int X = q / 1280, r = q - X*1280, m = r >> 7, j = r & 127;
    float a0 = 0.f, a1 = 0.f;
    const uint2* wp = (const uint2*)(p.WctP45 + (X << 15)) + j;
    const unsigned* mb = Su + MB + X*1280 + m*128;
    #pragma unroll 4
    for (int k2 = 0; k2 < 128; ++k2) {
      uint2 w = wp[k2 << 7];
      unsigned u = mb[k2];
      a0 = dot2(u, w.x, a0);
      a1 = dot2(u, w.y, a1);
    }
    Su[P45 + q] = packbf2(a0, a1);
  }
  __syncthreads();

  for (int di = 1; di < L_; ++di) {
    // ---- R1: gates (all, fp8) then {dA | dB | PH fp8 split-k-4 on 768 thr} ----
    {
      const float pre = p.prehg[(size_t)(((di-1) << 7) | b)*1024 + t];
      int kq = t & 3;
      const uint2* wr = p.W8g + t;
      const unsigned* xp = Su + HP + kq;
      float p0 = 0.f, p1 = 0.f, p2 = 0.f, p3 = 0.f;
      #pragma unroll 8
      for (int i = 0; i < 32; ++i) {
        uint2 w = wr[(size_t)i << 10];
        dot8fp8(w, xp[4*i], p0, p1, p2, p3);
      }
      p0 += __shfl_xor(p0, 1); p1 += __shfl_xor(p1, 1); p2 += __shfl_xor(p2, 1); p3 += __shfl_xor(p3, 1);
      p0 += __shfl_xor(p0, 2); p1 += __shfl_xor(p1, 2); p2 += __shfl_xor(p2, 2); p3 += __shfl_xor(p3, 2);
      float sel = (kq == 0) ? p0 : (kq == 1) ? p1 : (kq == 2) ? p2 : p3;
      Sf[GA + t] = pre + sel;
    }
    if (t < 128) {            // dA (hist slot di-1 = HV) — bf16
      int kq = t & 3;
      const uint4* wr = (const uint4*)p.W4da + (size_t)di*4096 + t;
      const unsigned* xp = Su + HV + ((t >> 5) << 7) + kq;
      float p0 = 0.f, p1 = 0.f, p2 = 0.f, p3 = 0.f;
      #pragma unroll 8
      for (int i = 0; i < 32; ++i) {
        uint4 w = wr[i << 7];
        unsigned x = xp[4*i];
        p0 = dot2(x, w.x, p0); p1 = dot2(x, w.y, p1);
        p2 = dot2(x, w.z, p2); p3 = dot2(x, w.w, p3);
      }
      p0 += __shfl_xor(p0, 1); p1 += __shfl_xor(p1, 1); p2 += __shfl_xor(p2, 1); p3 += __shfl_xor(p3, 1);
      p0 += __shfl_xor(p0, 2); p1 += __shfl_xor(p1, 2); p2 += __shfl_xor(p2, 2); p3 += __shfl_xor(p3, 2);
      float sel = (kq == 0) ? p0 : (kq == 1) ? p1 : (kq == 2) ? p2 : p3;
      Sf[DA + t] = sel;
    } else if (t < 256) {     // dB (prev h) — bf16
      int c = t - 128, kq = c & 3;
      const uint4* wr = (const uint4*)p.W4db + c;
      const unsigned* xp = Su + HP + kq;
      float p0 = 0.f, p1 = 0.f, p2 = 0.f, p3 = 0.f;
      #pragma unroll 8
      for (int i = 0; i < 32; ++i) {
        uint4 w = wr[i << 7];
        unsigned x = xp[4*i];
        p0 = dot2(x, w.x, p0); p1 = dot2(x, w.y, p1);
        p2 = dot2(x, w.z, p2); p3 = dot2(x, w.w, p3);
      }
      p0 += __shfl_xor(p0, 1); p1 += __shfl_xor(p1, 1); p2 += __shfl_xor(p2, 1); p3 += __shfl_xor(p3, 1);
      p0 += __shfl_xor(p0, 2); p1 += __shfl_xor(p1, 2); p2 += __shfl_xor(p2, 2); p3 += __shfl_xor(p3, 2);
      float sel = (kq == 0) ? p0 : (kq == 1) ? p1 : (kq == 2) ? p2 : p3;
      Sf[DB + c] = sel;
    } else {                  // PH append: fp8 split-k-4, 768 threads
      int q = t - 256;
      int X = q >> 8, rr = q & 255, ob = rr >> 2, kq = rr & 3;
      const uint2* wr = p.W8ph + q;
      const unsigned* xp = Su + HV + (X << 7) + kq;
      float p0 = 0.f, p1 = 0.f, p2 = 0.f, p3 = 0.f;
      #pragma unroll 8
      for (int i = 0; i < 32; ++i) {
        uint2 w = wr[i*768];
        dot8fp8(w, xp[4*i], p0, p1, p2, p3);
      }
      p0 += __shfl_xor(p0, 1); p1 += __shfl_xor(p1, 1); p2 += __shfl_xor(p2, 1); p3 += __shfl_xor(p3, 1);
      p0 += __shfl_xor(p0, 2); p1 += __shfl_xor(p1, 2); p2 += __shfl_xor(p2, 2); p3 += __shfl_xor(p3, 2);
      int phbase = PH + (X*30 + di-1)*128;
      if (kq == 0)       Su[phbase + 2*ob]     = packbf2(p0, p1);
      else if (kq == 2)  Su[phbase + 2*ob + 1] = packbf2(p2, p3);
    }
    __syncthreads();
    // ---- R2: sw ∥ QM ∥ M0 (bf16) ----
    if (t < 96) {
      float a = Sf[ACA + t] + Sf[DA + t];
      Sf[ACA + t] = a;
      Sf[SW + t] = ftanh(a + Sf[DB + t] + Sf[BH + t]);
    } else if (t >= 128 && t < 224) {   // QM append for slot di-1
      int q = t - 128, X = q >> 5, r = q & 31, kq = r & 3;
      const uint4* wr = (const uint4*)p.W4qm + q;
      const unsigned* xp = Su + HV + (X << 7) + kq;
      float p0 = 0.f, p1 = 0.f, p2 = 0.f, p3 = 0.f;
      #pragma unroll 8
      for (int i = 0; i < 32; ++i) {
        uint4 w = wr[i*96];
        unsigned x = xp[4*i];
        p0 = dot2(x, w.x, p0); p1 = dot2(x, w.y, p1);
        p2 = dot2(x, w.z, p2); p3 = dot2(x, w.w, p3);
      }
      p0 += __shfl_xor(p0, 1); p1 += __shfl_xor(p1, 1); p2 += __shfl_xor(p2, 1); p3 += __shfl_xor(p3, 1);
      p0 += __shfl_xor(p0, 2); p1 += __shfl_xor(p1, 2); p2 += __shfl_xor(p2, 2); p3 += __shfl_xor(p3, 2);
      float sel = (kq == 0) ? p0 : (kq == 1) ? p1 : (kq == 2) ? p2 : p3;
      Sf[QM + (X*30 + di-1)*32 + r] = sel;
    } else if (t >= 224 && t < 256) {   // M0
      int r = t - 224, kq = r & 3;
      const uint4* wr = (const uint4*)p.W4m0 + r;
      const unsigned* xp = Su + HP + kq;
      float p0 = 0.f, p1 = 0.f, p2 = 0.f, p3 = 0.f;
      #pragma unroll 8
      for (int i = 0; i < 32; ++i) {
        uint4 w = wr[i << 5];
        unsigned x = xp[4*i];
        p0 = dot2(x, w.x, p0); p1 = dot2(x, w.y, p1);
        p2 = dot2(x, w.z, p2); p3 = dot2(x, w.w, p3);
      }
      p0 += __shfl_xor(p0, 1); p1 += __shfl_xor(p1, 1); p2 += __shfl_xor(p2, 1); p3 += __shfl_xor(p3, 1);
      p0 += __shfl_xor(p0, 2); p1 += __shfl_xor(p1, 2); p2 += __shfl_xor(p2, 2); p3 += __shfl_xor(p3, 2);
      float sel = (kq == 0) ? p0 : (kq == 1) ? p1 : (kq == 2) ? p2 : p3;
      Sf[M0 + r] = sel;
    }
    __syncthreads();
    // ---- R3: swm (serial, conflict-free) ----
    if (t < 32) {
      bool valid = (t < 10) || (t >= 16 && t < 26);
      if (valid) {
        float aN = 0.f, aK = 0.f, aV = 0.f;
        const float* sw0 = Sf + SW;
        const float* q0 = Sf + QM + t;
        for (int l = 0; l < di; ++l) {
          aN = fmaf(sw0[l],      q0[l*32],        aN);
          aK = fmaf(sw0[32 + l], q0[960 + l*32],  aK);
          aV = fmaf(sw0[64 + l], q0[1920 + l*32], aV);
        }
        Sf[SWM + t] = ftanh(Sf[M0 + t] + Sf[BM + t] + aN + aK + aV);
      }
    }
    __syncthreads();
    // ---- R4: c0 + LSTM cell (conflict-free) ----
    if (t < 128) {
      float a0 = Sf[BCT + 2*t], a1 = Sf[BCT + 2*t + 1];
      for (int X = 0; X < 3; ++X) {
        const float* swp = Sf + SW + X*32;
        const unsigned* php = Su + PH + X*3840 + t;
        float e0 = 0.f, e1 = 0.f, o0 = 0.f, o1 = 0.f;
        int l = 0;
        for (; l + 1 < di; l += 2) {
          float s0 = swp[l], s1 = swp[l+1];
          unsigned ua = php[l*128], ub = php[(l+1)*128];
          e0 = fmaf(s0, u2lo(ua), e0); e1 = fmaf(s0, u2hi(ua), e1);
          o0 = fmaf(s1, u2lo(ub), o0); o1 = fmaf(s1, u2hi(ub), o1);
        }
        if (l < di) {
          float s = swp[l]; unsigned u = php[l*128];
          e0 = fmaf(s, u2lo(u), e0); e1 = fmaf(s, u2hi(u), e1);
        }
        a0 += e0 + o0; a1 += e1 + o1;
      }
      {
        float pp0 = 0.f, pp1 = 0.f, qq0 = 0.f, qq1 = 0.f;
        #pragma unroll
        for (int m = 0; m < 10; ++m) {
          float sk = Sf[SWM + m], sv = Sf[SWM + 16 + m];
          unsigned uk = Su[P45 + m*128 + t], uv = Su[P45 + 1280 + m*128 + t];
          pp0 = fmaf(sk, u2lo(uk), pp0); pp1 = fmaf(sk, u2hi(uk), pp1);
          qq0 = fmaf(sv, u2lo(uv), qq0); qq1 = fmaf(sv, u2hi(uv), qq1);
        }
        a0 += pp0 + qq0; a1 += pp1 + qq1;
      }
      int n0 = 2*t;
      float gi0 = Sf[GA+n0],   gf0 = Sf[GA+256+n0], gg0 = Sf[GA+512+n0], go0 = Sf[GA+768+n0];
      float gi1 = Sf[GA+n0+1], gf1 = Sf[GA+257+n0], gg1 = Sf[GA+513+n0], go1 = Sf[GA+769+n0];
      float cc0 = sigf(gf0)*a0 + sigf(gi0)*ftanh(gg0);
      float cc1 = sigf(gf1)*a1 + sigf(gi1)*ftanh(gg1);
      float h0 = sigf(go0)*ftanh(cc0);
      float h1 = sigf(go1)*ftanh(cc1);
      Su[HP + t] = packbf2(h0, h1);
    }
    __syncthreads();
    // ---- R5: hN/hK/hV fp8 split-k-4 (768 thr) + gt ----
    if (t < 768) {
      int ob = t >> 2, kq = t & 3;
      const uint2* wr = p.W8nkv + t;
      const unsigned* xp = Su + HP + kq;
      float p0 = 0.f, p1 = 0.f, p2 = 0.f, p3 = 0.f;
      #pragma unroll 8
      for (int i = 0; i < 32; ++i) {
        uint2 w = wr[i*768];
        dot8fp8(w, xp[4*i], p0, p1, p2, p3);
      }
      p0 += __shfl_xor(p0, 1); p1 += __shfl_xor(p1, 1); p2 += __shfl_xor(p2, 1); p3 += __shfl_xor(p3, 1);
      p0 += __shfl_xor(p0, 2); p1 += __shfl_xor(p1, 2); p2 += __shfl_xor(p2, 2); p3 += __shfl_xor(p3, 2);
      if ((kq & 1) == 0) {
        int thv = 2*ob + (kq >> 1);
        unsigned up = (kq == 0) ? packbf2(p0, p1) : packbf2(p2, p3);
        Su[HV + thv] = up;
        if (thv < 128) {
          int tile = di - 1;
          p.hNb[(size_t)((tile << 7) | b)*128 + thv] = up;
          int idx = ((((tile*4 + (b>>5))*8 + (thv>>4))*64 + ((thv>>2)&3)*16 + (b&15))*2 + ((b>>4)&1))*4 + (thv&3);
          p.hNbT[idx] = up;
        }
      }
    } else if (t >= 768 && t < 832) {
      int j = t - 768;
      float a = dot2(Su[HP + 2*j], p.WgP[2*j], 0.f);
      a = dot2(Su[HP + 2*j + 1], p.WgP[2*j + 1], a);
      #pragma unroll
      for (int o = 1; o < 64; o <<= 1) a += __shfl_xor(a, o);
      if (j == 0) {
        float g = sigf(a + Sf[BG]);
        p.gt_all[((di-1) << 7) | b] = g;
        p.outg[b*L_ + di] = g;
      }
    }
    __syncthreads();
  }
}

// ---------------------------------------------------------------- vocab GEMM: B in registers, A coalesced from hNbT
__global__ __launch_bounds__(256) void k_vocab(
    const unsigned* hNbT, const float* W_nv, const float* b_nv, float2* pmps) {
  extern __shared__ char smv[];   // 64 rows x 256 bf16, swizzled (32KB)
  int ch = blockIdx.x;            // 0..499
  int t = threadIdx.x, wid = t >> 6, lane = t & 63;
  int v0 = ch * 64;
  for (int i = t; i < 64*32; i += 256) {
    int r = i >> 5, c8 = i & 31;
    const float* wsrc = W_nv + (size_t)(v0 + r)*H_ + c8*8;
    float4 f0 = *(const float4*)wsrc, f1 = *(const float4*)(wsrc + 4);
    int4 v;
    v.x = (int)packbf2(f0.x, f0.y); v.y = (int)packbf2(f0.z, f0.w);
    v.z = (int)packbf2(f1.x, f1.y); v.w = (int)packbf2(f1.z, f1.w);
    *(int4*)(smv + ((r*512 + c8*16) ^ ((r&7)<<4))) = v;
  }
  float bb4[4];
  #pragma unroll
  for (int fj = 0; fj < 4; ++fj) bb4[fj] = b_nv[v0 + fj*16 + (lane & 15)];
  __syncthreads();
  bf16x8 Breg[8][4];
  #pragma unroll
  for (int kk = 0; kk < 8; ++kk) {
    int kb2 = kk*64 + (lane>>4)*16;
    #pragma unroll
    for (int fj = 0; fj < 4; ++fj) {
      int n = fj*16 + (lane & 15);
      Breg[kk][fj] = *(const bf16x8*)(smv + ((n*512 + kb2) ^ ((n&7)<<4)));
    }
  }
  const int4* At = (const int4*)hNbT;
  for (int tile = 0; tile < 29; ++tile) {
    f32x4 acc[2][4] = {};
    #pragma unroll
    for (int kk = 0; kk < 8; ++kk) {
      bf16x8 af[2];
      #pragma unroll
      for (int fi = 0; fi < 2; ++fi) {
        int4 u = At[((tile*4 + wid)*8 + kk)*128 + lane*2 + fi];
        af[fi] = __builtin_bit_cast(bf16x8, u);
      }
      #pragma unroll
      for (int fi = 0; fi < 2; ++fi)
        #pragma unroll
        for (int fj = 0; fj < 4; ++fj)
          acc[fi][fj] = MFMA(af[fi], Breg[kk][fj], acc[fi][fj]);
    }
    #pragma unroll
    for (int fi = 0; fi < 2; ++fi)
      #pragma unroll
      for (int r = 0; r < 4; ++r) {
        float mi = acc[fi][0][r] + bb4[0];
        #pragma unroll
        for (int fj = 1; fj < 4; ++fj) mi = fmaxf(mi, acc[fi][fj][r] + bb4[fj]);
        for (int o = 1; o < 16; o <<= 1) mi = fmaxf(mi, __shfl_xor(mi, o));
        float si = 0.f;
        #pragma unroll
        for (int fj = 0; fj < 4; ++fj) si += __expf(acc[fi][fj][r] + bb4[fj] - mi);
        for (int o = 1; o < 16; o <<= 1) si += __shfl_xor(si, o);
        if ((lane & 15) == 0) {
          int row = wid*32 + fi*16 + (lane>>4)*4 + r;
          pmps[(size_t)(tile*128 + row)*512 + ch] = make_float2(mi, si);
        }
      }
  }
}

// ---------------------------------------------------------------- per-step loss combine
__global__ __launch_bounds__(128) void k_combine(
    const float2* pmps, const unsigned* hNb, const float* W_nv, const float* b_nv,
    const float* gt_all, const int* sentence, float* loss_part) {
  __shared__ float red[128];
  int tile = blockIdx.x, bb = threadIdx.x;
  int g = tile*128 + bb;
  float M = -1e30f, Ssum = 0.f;
  const float2* pv = pmps + (size_t)g*512;
  #pragma unroll 4
  for (int c = 0; c < NCHK; ++c) {
    float2 v = pv[c];
    float M2 = fmaxf(M, v.x);
    Ssum = Ssum*__expf(M - M2) + v.y*__expf(v.x - M2);
    M = M2;
  }
  int tok = sentence[bb*L_ + tile + 1];
  float z = b_nv[tok];
  const unsigned* hu = hNb + (size_t)g*128;
  const float* wr = W_nv + (size_t)tok*H_;
  #pragma unroll 8
  for (int k = 0; k < 128; ++k) {
    unsigned w2 = hu[k];
    z += u2lo(w2)*wr[2*k] + u2hi(w2)*wr[2*k + 1];
  }
  float term = -(z - M - __logf(Ssum) + __logf(gt_all[g]));
  red[bb] = term;
  __syncthreads();
  for (int o = 64; o > 0; o >>= 1) {
    if (bb < o) red[bb] += red[bb + o];
    __syncthreads();
  }
  if (bb == 0) loss_part[tile] = red[0];
}

__global__ __launch_bounds__(64) void k_fin(const float* lp, float* out) {
  int t = threadIdx.x;
  float v = (t < 29) ? lp[t] : 0.f;
  for (int o = 1; o < 64; o <<= 1) v += __shfl_xor(v, o);
  if (t == 0) out[0] = v;
}

// ---------------------------------------------------------------- launch
extern "C" void kernel_launch(void* const* d_in, const int* in_sizes, int n_in,
                              void* d_out, int out_size, void* d_ws, size_t ws_size,
                              hipStream_t stream) {
  const int* sentence  = (const int*)d_in[0];
  const int* keywords  = (const int*)d_in[1];
  const int* categories= (const int*)d_in[2];
  const int* memsz     = (const int*)d_in[3];
  const float* emb  = (const float*)d_in[5];
  const float* W_ct = (const float*)d_in[6];
  const float* b_ct = (const float*)d_in[7];
  const float* W_ih = (const float*)d_in[8];
  const float* W_hh = (const float*)d_in[9];
  const float* b_ih = (const float*)d_in[10];
  const float* b_hh = (const float*)d_in[11];
  const float* W_n  = (const float*)d_in[12];
  const float* W_k  = (const float*)d_in[13];
  const float* W_v  = (const float*)d_in[14];
  const float* W_nv = (const float*)d_in[15];
  const float* b_nv = (const float*)d_in[16];
  const float* W_g  = (const float*)d_in[17];
  const float* b_g  = (const float*)d_in[18];
  const float* W_hn = (const float*)d_in[19];
  const float* b_hn = (const float*)d_in[20];
  const float* W_hk = (const float*)d_in[21];
  const float* b_hk = (const float*)d_in[22];
  const float* W_hv = (const float*)d_in[23];
  const float* b_hv = (const float*)d_in[24];
  const float* W_mk = (const float*)d_in[25];
  const float* b_mk = (const float*)d_in[26];
  const float* W_mv = (const float*)d_in[27];
  const float* b_mv = (const float*)d_in[28];
  float* out = (float*)d_out;

  char* wsp = (char*)d_ws;
  size_t off = 0;
  auto alloc = [&](size_t bytes) -> void* {
    void* pp = wsp + off;
    off = (off + bytes + 255) & ~(size_t)255;
    return pp;
  };
  uint2* W8g       = (uint2*)alloc((size_t)32768*8);
  uint2* W8nkv     = (uint2*)alloc((size_t)24576*8);
  uint2* W8ph      = (uint2*)alloc((size_t)24576*8);
  unsigned* WctP45 = (unsigned*)alloc((size_t)65536*4);
  unsigned* W4m0   = (unsigned*)alloc((size_t)4096*4);
  unsigned* W4qm   = (unsigned*)alloc((size_t)12288*4);
  unsigned* W4da   = (unsigned*)alloc((size_t)491520*4);
  unsigned* W4db   = (unsigned*)alloc((size_t)16384*4);
  unsigned* WgP    = (unsigned*)alloc((size_t)128*4);
  float* prehg     = (float*)alloc((size_t)29*B_*1024*4);
  unsigned* hNb    = (unsigned*)alloc((size_t)29*B_*128*4);
  unsigned* hNbT   = (unsigned*)alloc((size_t)29*B_*128*4);
  float* gt_all    = (float*)alloc((size_t)29*B_*4);
  float2* pmps     = (float2*)alloc((size_t)NG*512*8);
  float* loss_part = (float*)alloc(29*4);

  k_prep<<<744, 256, 131072, stream>>>(W_ct, W_hh, W_n, W_k, W_v,
      W_hn, W_hk, W_hv, W_mk, W_mv, W_g,
      W8g, W8nkv, W8ph, WctP45, W4m0, W4qm, W4da, W4db, WgP,
      sentence, emb, W_ih, b_ih, b_hh, prehg);

  LoopP P;
  P.sentence = sentence; P.keywords = keywords; P.categories = categories; P.memsz = memsz;
  P.emb = emb;
  P.W8g = W8g; P.W8nkv = W8nkv; P.W8ph = W8ph;
  P.WctP45 = WctP45; P.W4m0 = W4m0; P.W4qm = W4qm; P.W4da = W4da; P.W4db = W4db; P.WgP = WgP;
  P.prehg = prehg;
  P.b_ct = b_ct; P.b_hn = b_hn; P.b_hk = b_hk; P.b_hv = b_hv;
  P.b_mk = b_mk; P.b_mv = b_mv; P.b_g = b_g;
  P.hNb = hNb; P.hNbT = hNbT; P.gt_all = gt_all; P.outg = out + 1;

  k_loop<<<B_, 1024, 87812, stream>>>(P);
  k_vocab<<<NCHK, 256, 32768, stream>>>(hNbT, W_nv, b_nv, pmps);
  k_combine<<<29, 128, 0, stream>>>(pmps, hNb, W_nv, b_nv, gt_all, sentence, loss_part);
  k_fin<<<1, 64, 0, stream>>>(loss_part, out);
}

// Round 15
// 658.460 us; speedup vs baseline: 1.2427x; 1.2427x over previous
//
#include <hip/hip_runtime.h>
#include <math.h>

#define B_ 128
#define L_ 30
#define M_ 10
#define H_ 256
#define VN_ 32000
#define NCHK 500     // vocab chunks of 64 cols
#define NG 3712      // 29*128 rows

typedef __bf16 bf16;
typedef bf16 bf16x8 __attribute__((ext_vector_type(8)));
typedef float f32x4 __attribute__((ext_vector_type(4)));

#define MFMA(a,b,c) __builtin_amdgcn_mfma_f32_16x16x32_bf16(a, b, c, 0, 0, 0)

__device__ __forceinline__ float rcpf(float x) { return __builtin_amdgcn_rcpf(x); }
__device__ __forceinline__ float sigf(float x) { return rcpf(1.f + __expf(-x)); }
__device__ __forceinline__ float ftanh(float x) {
  float e = __expf(2.f * x);
  return 1.f - 2.f * rcpf(e + 1.f);
}
__device__ __forceinline__ float u2lo(unsigned w) { return __builtin_bit_cast(float, w << 16); }
__device__ __forceinline__ float u2hi(unsigned w) { return __builtin_bit_cast(float, w & 0xffff0000u); }
__device__ __forceinline__ unsigned packbf2(float a, float b) {
  unsigned short lo = __builtin_bit_cast(unsigned short, (bf16)a);
  unsigned short hi = __builtin_bit_cast(unsigned short, (bf16)b);
  return (unsigned)lo | ((unsigned)hi << 16);
}

#if __has_builtin(__builtin_amdgcn_fdot2_f32_bf16)
typedef __bf16 bf16x2 __attribute__((ext_vector_type(2)));
__device__ __forceinline__ float dot2(unsigned x, unsigned w, float c) {
  return __builtin_amdgcn_fdot2_f32_bf16(__builtin_bit_cast(bf16x2, x),
                                         __builtin_bit_cast(bf16x2, w), c, false);
}
#else
__device__ __forceinline__ float dot2(unsigned x, unsigned w, float c) {
  c = fmaf(u2lo(x), u2lo(w), c);
  return fmaf(u2hi(x), u2hi(w), c);
}
#endif

// ---------------------------------------------------------------- weight prep (+ fused pregates, blocks >= 512)
// Thread-major uint4 bf16 layouts (round-10 proven): at iteration i, thread t
// loads uint4 (4 bf16-pairs = 4 outputs at one k2); lane-consecutive uint4 are
// address-consecutive (1KB/wave coalesced).
__global__ __launch_bounds__(256) void k_prep(
    const float* W_ct, const float* W_hh,
    const float* W_n, const float* W_k, const float* W_v,
    const float* W_hn, const float* W_hk, const float* W_hv,
    const float* W_mk, const float* W_mv, const float* W_g,
    unsigned* W4g, unsigned* W4nkv, unsigned* W4ph, unsigned* WctP45,
    unsigned* W4m0, unsigned* W4qm, unsigned* W4da, unsigned* W4db, unsigned* WgP,
    const int* sentence, const float* emb, const float* W_ih,
    const float* b_ih, const float* b_hh, float* prehg) {
  if (blockIdx.x >= 512) {
    // ======== pregates: emb@W_ih via MFMA (29 x 8 blocks) ========
    extern __shared__ char smp[];
    char* Al = smp;
    char* Bl = smp + 65536;
    __shared__ int tok_s[128];
    int blk = blockIdx.x - 512;
    int gd = blk >> 3, nc = blk & 7;
    int t = threadIdx.x, wid = t >> 6, lane = t & 63;
    if (t < 128) tok_s[t] = sentence[t*L_ + gd];
    __syncthreads();
    for (int i = t; i < 128*32; i += 256) {
      int r = i >> 5, c8 = i & 31;
      const float* e = emb + (size_t)tok_s[r]*H_ + c8*8;
      float4 f0 = *(const float4*)e, f1 = *(const float4*)(e + 4);
      int4 v;
      v.x = (int)packbf2(f0.x, f0.y); v.y = (int)packbf2(f0.z, f0.w);
      v.z = (int)packbf2(f1.x, f1.y); v.w = (int)packbf2(f1.z, f1.w);
      *(int4*)(Al + ((r*512 + c8*16) ^ ((r&7)<<4))) = v;
      const float* wsrc = W_ih + (size_t)(nc*128 + r)*H_ + c8*8;
      float4 g0 = *(const float4*)wsrc, g1 = *(const float4*)(wsrc + 4);
      int4 w;
      w.x = (int)packbf2(g0.x, g0.y); w.y = (int)packbf2(g0.z, g0.w);
      w.z = (int)packbf2(g1.x, g1.y); w.w = (int)packbf2(g1.z, g1.w);
      *(int4*)(Bl + ((r*512 + c8*16) ^ ((r&7)<<4))) = w;
    }
    __syncthreads();
    f32x4 acc[2][8] = {};
    #pragma unroll 2
    for (int kk = 0; kk < 8; ++kk) {
      int kb2 = kk*64 + (lane>>4)*16;
      bf16x8 af[2], bfr[8];
      #pragma unroll
      for (int fi = 0; fi < 2; ++fi) {
        int m = wid*32 + fi*16 + (lane & 15);
        af[fi] = *(const bf16x8*)(Al + ((m*512 + kb2) ^ ((m&7)<<4)));
      }
      #pragma unroll
      for (int fj = 0; fj < 8; ++fj) {
        int n = fj*16 + (lane & 15);
        bfr[fj] = *(const bf16x8*)(Bl + ((n*512 + kb2) ^ ((n&7)<<4)));
      }
      #pragma unroll
      for (int fi = 0; fi < 2; ++fi)
        #pragma unroll
        for (int fj = 0; fj < 8; ++fj)
          acc[fi][fj] = MFMA(af[fi], bfr[fj], acc[fi][fj]);
    }
    #pragma unroll
    for (int fi = 0; fi < 2; ++fi)
      #pragma unroll
      for (int fj = 0; fj < 8; ++fj)
        #pragma unroll
        for (int r = 0; r < 4; ++r) {
          int row = wid*32 + fi*16 + (lane>>4)*4 + r;
          int col = nc*128 + fj*16 + (lane & 15);
          prehg[((size_t)gd*128 + row)*1024 + col] = acc[fi][fj][r] + b_ih[col] + b_hh[col];
        }
    return;
  }
  int stride = 512 * blockDim.x;
  int base = blockIdx.x * blockDim.x + threadIdx.x;
  // W4g: [i 32][t 1024][s 4]: n=4*(t>>2)+s, k2=(t&3)+4*i
  for (int idx = base; idx < 131072; idx += stride) {
    int s = idx & 3, tt = (idx >> 2) & 1023, i = idx >> 12;
    int n = 4*(tt >> 2) + s, k2 = (tt & 3) + 4*i;
    W4g[idx] = packbf2(W_hh[n*256 + 2*k2], W_hh[n*256 + 2*k2 + 1]);
  }
  // W4nkv: [i 64][t 384][s 4]: n=4*(t>>1)+s, k2=(t&1)+2*i   (round-10 split-k-2)
  for (int idx = base; idx < 98304; idx += stride) {
    int s = idx & 3, r2 = idx >> 2, tt = r2 % 384, i = r2 / 384;
    int n = 4*(tt >> 1) + s, k2 = (tt & 1) + 2*i;
    const float* src = (n < 256) ? W_n : (n < 512) ? W_k : W_v;
    int nn = n & 255;
    W4nkv[idx] = packbf2(src[nn*256 + 2*k2], src[nn*256 + 2*k2 + 1]);
  }
  // W4ph: [i 64][q 384][s 4]: X=q>>7, r=q&127, j2=r>>1, kh=r&1; nl=4*j2+s, k2=kh+2*i
  for (int idx = base; idx < 98304; idx += stride) {
    int s = idx & 3, r2 = idx >> 2, q = r2 % 384, i = r2 / 384;
    int X = q >> 7, r = q & 127, j2 = r >> 1, kh = r & 1;
    int nl = 4*j2 + s, k2 = kh + 2*i;
    int col = X*256 + 2*k2;
    W4ph[idx] = packbf2(W_ct[nl*1280 + col], W_ct[nl*1280 + col + 1]);
  }
  // WctP45 (init-only, uint2-style bf16 [X 2][k2 128][n 256])
  for (int i = base; i < 65536; i += stride) {
    int X = i >> 15, r = i & 32767, k2 = r >> 8, n = r & 255;
    int col = 768 + X*256 + 2*k2;
    WctP45[i] = packbf2(W_ct[n*1280 + col], W_ct[n*1280 + col + 1]);
  }
  // W4m0: [i 32][t 32][s 4]
  for (int idx = base; idx < 4096; idx += stride) {
    int s = idx & 3, tt = (idx >> 2) & 31, i = idx >> 7;
    int c = 4*(tt >> 2) + s, k2 = (tt & 3) + 4*i;
    float x0 = 0.f, x1 = 0.f;
    if (c < 10)              { x0 = W_mk[c*1024 + 2*k2]; x1 = W_mk[c*1024 + 2*k2 + 1]; }
    else if (c >= 16 && c < 26) { int m = c-16; x0 = W_mv[m*1024 + 2*k2]; x1 = W_mv[m*1024 + 2*k2 + 1]; }
    W4m0[idx] = packbf2(x0, x1);
  }
  // W4qm: [i 32][q 96][s 4]
  for (int idx = base; idx < 12288; idx += stride) {
    int s = idx & 3, r2 = idx >> 2, q = r2 % 96, i = r2 / 96;
    int X = q >> 5, r = q & 31;
    int c = 4*(r >> 2) + s, k2 = (r & 3) + 4*i;
    int off = 256 + X*256 + 2*k2;
    float x0 = 0.f, x1 = 0.f;
    if (c < 10)              { x0 = W_mk[c*1024 + off]; x1 = W_mk[c*1024 + off + 1]; }
    else if (c >= 16 && c < 26) { int m = c-16; x0 = W_mv[m*1024 + off]; x1 = W_mv[m*1024 + off + 1]; }
    W4qm[idx] = packbf2(x0, x1);
  }
  // W4da: [d 30][i 32][t 128][s 4]
  for (int idx = base; idx < 491520; idx += stride) {
    int s = idx & 3, tt = (idx >> 2) & 127, i = (idx >> 9) & 31, d = idx >> 14;
    int c = 4*(tt >> 2) + s, k2 = (tt & 3) + 4*i;
    float x0 = 0.f, x1 = 0.f;
    if (c < 96) {
      int X = c >> 5, l = c & 31;
      if (l < 30) {
        const float* W = (X == 0) ? W_hn : (X == 1) ? W_hk : W_hv;
        x0 = W[l*7936 + d*256 + 2*k2]; x1 = W[l*7936 + d*256 + 2*k2 + 1];
      }
    }
    W4da[idx] = packbf2(x0, x1);
  }
  // W4db: [i 32][t 128][s 4]
  for (int idx = base; idx < 16384; idx += stride) {
    int s = idx & 3, tt = (idx >> 2) & 127, i = idx >> 9;
    int c = 4*(tt >> 2) + s, k2 = (tt & 3) + 4*i;
    float x0 = 0.f, x1 = 0.f;
    if (c < 96) {
      int X = c >> 5, l = c & 31;
      if (l < 30) {
        const float* W = (X == 0) ? W_hn : (X == 1) ? W_hk : W_hv;
        x0 = W[l*7936 + 2*k2]; x1 = W[l*7936 + 2*k2 + 1];
      }
    }
    W4db[idx] = packbf2(x0, x1);
  }
  for (int i = base; i < 128; i += stride) WgP[i] = packbf2(W_g[2*i], W_g[2*i+1]);
}

// ---------------------------------------------------------------- recurrence (round-10 verbatim, best measured: 480us)
struct LoopP {
  const int *sentence, *keywords, *categories, *memsz;
  const float *emb;
  const unsigned *W4g, *W4nkv, *W4ph, *WctP45, *W4m0, *W4qm, *W4da, *W4db, *WgP;
  const float *prehg;
  const float *b_ct, *b_hn, *b_hk, *b_hv, *b_mk, *b_mv, *b_g;
  unsigned* hNb;
  unsigned* hNbT;
  float* gt_all;
  float* outg;
};

__global__ __launch_bounds__(1024) void k_loop(LoopP p) {
  extern __shared__ unsigned Su[];
  float* Sf = (float*)Su;
  const int t = threadIdx.x, b = blockIdx.x;
  enum { PH = 0, QM = 11520, P45 = 14400, MB = 16960,
         GA = 19520, HP = 20544, HV = 20672,
         SW = 21056, ACA = 21152, SWM = 21248, M0 = 21280,
         DA = 21312, DB = 21440,
         BCT = 21568, BH = 21824, BM = 21920, BG = 21952 };

  // ===== init =====
  for (int i = t; i < 2560; i += 1024) {
    int X = i / 1280, r = i - X*1280, m = r >> 7, j = r & 127;
    int ms = p.memsz[b];
    int idx = (X == 0 ? p.keywords : p.categories)[b*M_ + m];
    unsigned u = 0;
    if (m < ms) {
      const float* e = p.emb + (size_t)idx*H_ + 2*j;
      u = packbf2(e[0], e[1]);
    }
    Su[MB + i] = u;
  }
  if (t < 256) Sf[BCT + t] = p.b_ct[t];
  if (t < 96) {
    int X = t >> 5, l = t & 31;
    const float* bh = (X == 0) ? p.b_hn : (X == 1) ? p.b_hk : p.b_hv;
    Sf[BH + t] = (l < 30) ? bh[l] : 0.f;
    Sf[ACA + t] = 0.f;
  }
  if (t < 32) {
    float v = 0.f;
    if (t < 10) v = p.b_mk[t];
    else if (t >= 16 && t < 26) v = p.b_mv[t - 16];
    Sf[BM + t] = v;
  }
  if (t == 0) { Sf[BG] = p.b_g[0]; p.outg[b*L_] = 0.f; }
  __syncthreads();
  if (t < 128) {
    float a0 = 0.f, a1 = 0.f;
    #pragma unroll
    for (int q = 0; q < 20; ++q) {
      unsigned u = Su[MB + q*128 + t];
      a0 += u2lo(u); a1 += u2hi(u);
    }
    float msf = (float)p.memsz[b];
    unsigned up = packbf2(a0 / (2.f * msf), a1 / (2.f * msf));
    Su[HP + t] = up;
    Su[HV + t] = up; Su[HV + 128 + t] = up; Su[HV + 256 + t] = up;
  }
  for (int q = t; q < 2560; q += 1024) {
    int X = q / 1280, r = q - X*1280, m = r >> 7, j = r & 127;
    float a0 = 0.f, a1 = 0.f;
    const uint2* wp = (const uint2*)(p.WctP45 + (X << 15)) + j;
    const unsigned* mb = Su + MB + X*1280 + m*128;
    #pragma unroll 4
    for (int k2 = 0; k2 < 128; ++k2) {
      uint2 w = wp[k2 << 7];
      unsigned u = mb[k2];
      a0 = dot2(u, w.x, a0);
      a1 = dot2(u, w.y, a1);
    }
    Su[P45 + q] = packbf2(a0, a1);
  }
  __syncthreads();

  for (int di = 1; di < L_; ++di) {
    // ---- R1: gates (all threads, uint4+butterfly) + aux GEVMs ----
    {
      const float pre = p.prehg[(size_t)(((di-1) << 7) | b)*1024 + t];
      int kq = t & 3;
      const uint4* wr = (const uint4*)p.W4g + t;
      const unsigned* xp = Su + HP + kq;
      float p0 = 0.f, p1 = 0.f, p2 = 0.f, p3 = 0.f;
      #pragma unroll 8
      for (int i = 0; i < 32; ++i) {
        uint4 w = wr[(size_t)i << 10];
        unsigned x = xp[4*i];
        p0 = dot2(x, w.x, p0); p1 = dot2(x, w.y, p1);
        p2 = dot2(x, w.z, p2); p3 = dot2(x, w.w, p3);
      }
      p0 += __shfl_xor(p0, 1); p1 += __shfl_xor(p1, 1); p2 += __shfl_xor(p2, 1); p3 += __shfl_xor(p3, 1);
      p0 += __shfl_xor(p0, 2); p1 += __shfl_xor(p1, 2); p2 += __shfl_xor(p2, 2); p3 += __shfl_xor(p3, 2);
      float sel = (kq == 0) ? p0 : (kq == 1) ? p1 : (kq == 2) ? p2 : p3;
      Sf[GA + t] = pre + sel;
    }
    if (t < 128) {            // dA (hist slot di-1 = HV)
      int kq = t & 3;
      const uint4* wr = (const uint4*)p.W4da + (size_t)di*4096 + t;
      const unsigned* xp = Su + HV + ((t >> 5) << 7) + kq;
      float p0 = 0.f, p1 = 0.f, p2 = 0.f, p3 = 0.f;
      #pragma unroll 8
      for (int i = 0; i < 32; ++i) {
        uint4 w = wr[i << 7];
        unsigned x = xp[4*i];
        p0 = dot2(x, w.x, p0); p1 = dot2(x, w.y, p1);
        p2 = dot2(x, w.z, p2); p3 = dot2(x, w.w, p3);
      }
      p0 += __shfl_xor(p0, 1); p1 += __shfl_xor(p1, 1); p2 += __shfl_xor(p2, 1); p3 += __shfl_xor(p3, 1);
      p0 += __shfl_xor(p0, 2); p1 += __shfl_xor(p1, 2); p2 += __shfl_xor(p2, 2); p3 += __shfl_xor(p3, 2);
      float sel = (kq == 0) ? p0 : (kq == 1) ? p1 : (kq == 2) ? p2 : p3;
      Sf[DA + t] = sel;
    } else if (t < 256) {     // dB (prev h)
      int c = t - 128, kq = c & 3;
      const uint4* wr = (const uint4*)p.W4db + c;
      const unsigned* xp = Su + HP + kq;
      float p0 = 0.f, p1 = 0.f, p2 = 0.f, p3 = 0.f;
      #pragma unroll 8
      for (int i = 0; i < 32; ++i) {
        uint4 w = wr[i << 7];
        unsigned x = xp[4*i];
        p0 = dot2(x, w.x, p0); p1 = dot2(x, w.y, p1);
        p2 = dot2(x, w.z, p2); p3 = dot2(x, w.w, p3);
      }
      p0 += __shfl_xor(p0, 1); p1 += __shfl_xor(p1, 1); p2 += __shfl_xor(p2, 1); p3 += __shfl_xor(p3, 1);
      p0 += __shfl_xor(p0, 2); p1 += __shfl_xor(p1, 2); p2 += __shfl_xor(p2, 2); p3 += __shfl_xor(p3, 2);
      float sel = (kq == 0) ? p0 : (kq == 1) ? p1 : (kq == 2) ? p2 : p3;
      Sf[DB + c] = sel;
    } else if (t < 640) {     // PH append: split-k-2, 384 threads
      int q = t - 256, X = q >> 7, r = q & 127, kh = r & 1;
      const uint4* wr = (const uint4*)p.W4ph + q;
      const unsigned* xp = Su + HV + (X << 7) + kh;
      float p0 = 0.f, p1 = 0.f, p2 = 0.f, p3 = 0.f;
      #pragma unroll 8
      for (int i = 0; i < 64; ++i) {
        uint4 w = wr[i*384];
        unsigned x = xp[2*i];
        p0 = dot2(x, w.x, p0); p1 = dot2(x, w.y, p1);
        p2 = dot2(x, w.z, p2); p3 = dot2(x, w.w, p3);
      }
      p0 += __shfl_xor(p0, 1); p1 += __shfl_xor(p1, 1); p2 += __shfl_xor(p2, 1); p3 += __shfl_xor(p3, 1);
      unsigned val = kh ? packbf2(p2, p3) : packbf2(p0, p1);
      Su[PH + (X*30 + di-1)*128 + r] = val;
    } else if (t < 736) {     // QM append
      int q = t - 640, X = q >> 5, r = q & 31, kq = r & 3;
      const uint4* wr = (const uint4*)p.W4qm + q;
      const unsigned* xp = Su + HV + (X << 7) + kq;
      float p0 = 0.f, p1 = 0.f, p2 = 0.f, p3 = 0.f;
      #pragma unroll 8
      for (int i = 0; i < 32; ++i) {
        uint4 w = wr[i*96];
        unsigned x = xp[4*i];
        p0 = dot2(x, w.x, p0); p1 = dot2(x, w.y, p1);
        p2 = dot2(x, w.z, p2); p3 = dot2(x, w.w, p3);
      }
      p0 += __shfl_xor(p0, 1); p1 += __shfl_xor(p1, 1); p2 += __shfl_xor(p2, 1); p3 += __shfl_xor(p3, 1);
      p0 += __shfl_xor(p0, 2); p1 += __shfl_xor(p1, 2); p2 += __shfl_xor(p2, 2); p3 += __shfl_xor(p3, 2);
      float sel = (kq == 0) ? p0 : (kq == 1) ? p1 : (kq == 2) ? p2 : p3;
      Sf[QM + (X*30 + di-1)*32 + r] = sel;
    } else if (t >= 768 && t < 800) {  // M0
      int r = t - 768, kq = r & 3;
      const uint4* wr = (const uint4*)p.W4m0 + r;
      const unsigned* xp = Su + HP + kq;
      float p0 = 0.f, p1 = 0.f, p2 = 0.f, p3 = 0.f;
      #pragma unroll 8
      for (int i = 0; i < 32; ++i) {
        uint4 w = wr[i << 5];
        unsigned x = xp[4*i];
        p0 = dot2(x, w.x, p0); p1 = dot2(x, w.y, p1);
        p2 = dot2(x, w.z, p2); p3 = dot2(x, w.w, p3);
      }
      p0 += __shfl_xor(p0, 1); p1 += __shfl_xor(p1, 1); p2 += __shfl_xor(p2, 1); p3 += __shfl_xor(p3, 1);
      p0 += __shfl_xor(p0, 2); p1 += __shfl_xor(p1, 2); p2 += __shfl_xor(p2, 2); p3 += __shfl_xor(p3, 2);
      float sel = (kq == 0) ? p0 : (kq == 1) ? p1 : (kq == 2) ? p2 : p3;
      Sf[M0 + r] = sel;
    }
    __syncthreads();
    // ---- R2: sw ----
    if (t < 96) {
      float a = Sf[ACA + t] + Sf[DA + t];
      Sf[ACA + t] = a;
      Sf[SW + t] = ftanh(a + Sf[DB + t] + Sf[BH + t]);
    }
    __syncthreads();
    // ---- R3: swm ----
    if (t < 32) {
      bool valid = (t < 10) || (t >= 16 && t < 26);
      if (valid) {
        float aN = 0.f, aK = 0.f, aV = 0.f;
        const float* sw0 = Sf + SW;
        const float* q0 = Sf + QM + t;
        for (int l = 0; l < di; ++l) {
          aN = fmaf(sw0[l],      q0[l*32],        aN);
          aK = fmaf(sw0[32 + l], q0[960 + l*32],  aK);
          aV = fmaf(sw0[64 + l], q0[1920 + l*32], aV);
        }
        Sf[SWM + t] = ftanh(Sf[M0 + t] + Sf[BM + t] + aN + aK + aV);
      }
    }
    __syncthreads();
    // ---- R4: c0 + LSTM cell ----
    if (t < 128) {
      float a0 = Sf[BCT + 2*t], a1 = Sf[BCT + 2*t + 1];
      for (int X = 0; X < 3; ++X) {
        const float* swp = Sf + SW + X*32;
        const unsigned* php = Su + PH + X*3840 + t;
        float e0 = 0.f, e1 = 0.f, o0 = 0.f, o1 = 0.f;
        int l = 0;
        for (; l + 1 < di; l += 2) {
          float s0 = swp[l], s1 = swp[l+1];
          unsigned ua = php[l*128], ub = php[(l+1)*128];
          e0 = fmaf(s0, u2lo(ua), e0); e1 = fmaf(s0, u2hi(ua), e1);
          o0 = fmaf(s1, u2lo(ub), o0); o1 = fmaf(s1, u2hi(ub), o1);
        }
        if (l < di) {
          float s = swp[l]; unsigned u = php[l*128];
          e0 = fmaf(s, u2lo(u), e0); e1 = fmaf(s, u2hi(u), e1);
        }
        a0 += e0 + o0; a1 += e1 + o1;
      }
      {
        float pp0 = 0.f, pp1 = 0.f, qq0 = 0.f, qq1 = 0.f;
        #pragma unroll
        for (int m = 0; m < 10; ++m) {
          float sk = Sf[SWM + m], sv = Sf[SWM + 16 + m];
          unsigned uk = Su[P45 + m*128 + t], uv = Su[P45 + 1280 + m*128 + t];
          pp0 = fmaf(sk, u2lo(uk), pp0); pp1 = fmaf(sk, u2hi(uk), pp1);
          qq0 = fmaf(sv, u2lo(uv), qq0); qq1 = fmaf(sv, u2hi(uv), qq1);
        }
        a0 += pp0 + qq0; a1 += pp1 + qq1;
      }
      int n0 = 2*t;
      float gi0 = Sf[GA+n0],   gf0 = Sf[GA+256+n0], gg0 = Sf[GA+512+n0], go0 = Sf[GA+768+n0];
      float gi1 = Sf[GA+n0+1], gf1 = Sf[GA+257+n0], gg1 = Sf[GA+513+n0], go1 = Sf[GA+769+n0];
      float cc0 = sigf(gf0)*a0 + sigf(gi0)*ftanh(gg0);
      float cc1 = sigf(gf1)*a1 + sigf(gi1)*ftanh(gg1);
      float h0 = sigf(go0)*ftanh(cc0);
      float h1 = sigf(go1)*ftanh(cc1);
      Su[HP + t] = packbf2(h0, h1);
    }
    __syncthreads();
    // ---- R5: hN/hK/hV (uint4 split-k-2) + gt ----
    if (t < 384) {
      int kh = t & 1;
      const uint4* wr = (const uint4*)p.W4nkv + t;
      const unsigned* xp = Su + HP + kh;
      float p0 = 0.f, p1 = 0.f, p2 = 0.f, p3 = 0.f;
      #pragma unroll 8
      for (int i = 0; i < 64; ++i) {
        uint4 w = wr[i*384];
        unsigned x = xp[2*i];
        p0 = dot2(x, w.x, p0); p1 = dot2(x, w.y, p1);
        p2 = dot2(x, w.z, p2); p3 = dot2(x, w.w, p3);
      }
      p0 += __shfl_xor(p0, 1); p1 += __shfl_xor(p1, 1); p2 += __shfl_xor(p2, 1); p3 += __shfl_xor(p3, 1);
      unsigned up = kh ? packbf2(p2, p3) : packbf2(p0, p1);
      Su[HV + t] = up;
      int X = t >> 7, j = t & 127;
      if (X == 0) {
        int tile = di - 1;
        p.hNb[(size_t)((tile << 7) | b)*128 + j] = up;
        int idx = ((((tile*4 + (b>>5))*8 + (j>>4))*64 + ((j>>2)&3)*16 + (b&15))*2 + ((b>>4)&1))*4 + (j&3);
        p.hNbT[idx] = up;
      }
    } else if (t >= 448 && t < 512) {
      int j = t - 448;
      float a = dot2(Su[HP + 2*j], p.WgP[2*j], 0.f);
      a = dot2(Su[HP + 2*j + 1], p.WgP[2*j + 1], a);
      #pragma unroll
      for (int o = 1; o < 64; o <<= 1) a += __shfl_xor(a, o);
      if (j == 0) {
        float g = sigf(a + Sf[BG]);
        p.gt_all[((di-1) << 7) | b] = g;
        p.outg[b*L_ + di] = g;
      }
    }
    __syncthreads();
  }
}

// ---------------------------------------------------------------- vocab GEMM: B in registers, A coalesced from hNbT
__global__ __launch_bounds__(256) void k_vocab(
    const unsigned* hNbT, const float* W_nv, const float* b_nv, float2* pmps) {
  extern __shared__ char smv[];   // 64 rows x 256 bf16, swizzled (32KB)
  int ch = blockIdx.x;            // 0..499
  int t = threadIdx.x, wid = t >> 6, lane = t & 63;
  int v0 = ch * 64;
  for (int i = t; i < 64*32; i += 256) {
    int r = i >> 5, c8 = i & 31;
    const float* wsrc = W_nv + (size_t)(v0 + r)*H_ + c8*8;
    float4 f0 = *(const float4*)wsrc, f1 = *(const float4*)(wsrc + 4);
    int4 v;
    v.x = (int)packbf2(f0.x, f0.y); v.y = (int)packbf2(f0.z, f0.w);
    v.z = (int)packbf2(f1.x, f1.y); v.w = (int)packbf2(f1.z, f1.w);
    *(int4*)(smv + ((r*512 + c8*16) ^ ((r&7)<<4))) = v;
  }
  float bb4[4];
  #pragma unroll
  for (int fj = 0; fj < 4; ++fj) bb4[fj] = b_nv[v0 + fj*16 + (lane & 15)];
  __syncthreads();
  bf16x8 Breg[8][4];
  #pragma unroll
  for (int kk = 0; kk < 8; ++kk) {
    int kb2 = kk*64 + (lane>>4)*16;
    #pragma unroll
    for (int fj = 0; fj < 4; ++fj) {
      int n = fj*16 + (lane & 15);
      Breg[kk][fj] = *(const bf16x8*)(smv + ((n*512 + kb2) ^ ((n&7)<<4)));
    }
  }
  const int4* At = (const int4*)hNbT;
  for (int tile = 0; tile < 29; ++tile) {
    f32x4 acc[2][4] = {};
    #pragma unroll
    for (int kk = 0; kk < 8; ++kk) {
      bf16x8 af[2];
      #pragma unroll
      for (int fi = 0; fi < 2; ++fi) {
        int4 u = At[((tile*4 + wid)*8 + kk)*128 + lane*2 + fi];
        af[fi] = __builtin_bit_cast(bf16x8, u);
      }
      #pragma unroll
      for (int fi = 0; fi < 2; ++fi)
        #pragma unroll
        for (int fj = 0; fj < 4; ++fj)
          acc[fi][fj] = MFMA(af[fi], Breg[kk][fj], acc[fi][fj]);
    }
    #pragma unroll
    for (int fi = 0; fi < 2; ++fi)
      #pragma unroll
      for (int r = 0; r < 4; ++r) {
        float mi = acc[fi][0][r] + bb4[0];
        #pragma unroll
        for (int fj = 1; fj < 4; ++fj) mi = fmaxf(mi, acc[fi][fj][r] + bb4[fj]);
        for (int o = 1; o < 16; o <<= 1) mi = fmaxf(mi, __shfl_xor(mi, o));
        float si = 0.f;
        #pragma unroll
        for (int fj = 0; fj < 4; ++fj) si += __expf(acc[fi][fj][r] + bb4[fj] - mi);
        for (int o = 1; o < 16; o <<= 1) si += __shfl_xor(si, o);
        if ((lane & 15) == 0) {
          int row = wid*32 + fi*16 + (lane>>4)*4 + r;
          pmps[(size_t)(tile*128 + row)*512 + ch] = make_float2(mi, si);
        }
      }
  }
}

// ---------------------------------------------------------------- per-step loss combine
__global__ __launch_bounds__(128) void k_combine(
    const float2* pmps, const unsigned* hNb, const float* W_nv, const float* b_nv,
    const float* gt_all, const int* sentence, float* loss_part) {
  __shared__ float red[128];
  int tile = blockIdx.x, bb = threadIdx.x;
  int g = tile*128 + bb;
  float M = -1e30f, Ssum = 0.f;
  const float2* pv = pmps + (size_t)g*512;
  #pragma unroll 4
  for (int c = 0; c < NCHK; ++c) {
    float2 v = pv[c];
    float M2 = fmaxf(M, v.x);
    Ssum = Ssum*__expf(M - M2) + v.y*__expf(v.x - M2);
    M = M2;
  }
  int tok = sentence[bb*L_ + tile + 1];
  float z = b_nv[tok];
  const unsigned* hu = hNb + (size_t)g*128;
  const float* wr = W_nv + (size_t)tok*H_;
  #pragma unroll 8
  for (int k = 0; k < 128; ++k) {
    unsigned w2 = hu[k];
    z += u2lo(w2)*wr[2*k] + u2hi(w2)*wr[2*k + 1];
  }
  float term = -(z - M - __logf(Ssum) + __logf(gt_all[g]));
  red[bb] = term;
  __syncthreads();
  for (int o = 64; o > 0; o >>= 1) {
    if (bb < o) red[bb] += red[bb + o];
    __syncthreads();
  }
  if (bb == 0) loss_part[tile] = red[0];
}

__global__ __launch_bounds__(64) void k_fin(const float* lp, float* out) {
  int t = threadIdx.x;
  float v = (t < 29) ? lp[t] : 0.f;
  for (int o = 1; o < 64; o <<= 1) v += __shfl_xor(v, o);
  if (t == 0) out[0] = v;
}

// ---------------------------------------------------------------- launch
extern "C" void kernel_launch(void* const* d_in, const int* in_sizes, int n_in,
                              void* d_out, int out_size, void* d_ws, size_t ws_size,
                              hipStream_t stream) {
  const int* sentence  = (const int*)d_in[0];
  const int* keywords  = (const int*)d_in[1];
  const int* categories= (const int*)d_in[2];
  const int* memsz     = (const int*)d_in[3];
  const float* emb  = (const float*)d_in[5];
  const float* W_ct = (const float*)d_in[6];
  const float* b_ct = (const float*)d_in[7];
  const float* W_ih = (const float*)d_in[8];
  const float* W_hh = (const float*)d_in[9];
  const float* b_ih = (const float*)d_in[10];
  const float* b_hh = (const float*)d_in[11];
  const float* W_n  = (const float*)d_in[12];
  const float* W_k  = (const float*)d_in[13];
  const float* W_v  = (const float*)d_in[14];
  const float* W_nv = (const float*)d_in[15];
  const float* b_nv = (const float*)d_in[16];
  const float* W_g  = (const float*)d_in[17];
  const float* b_g  = (const float*)d_in[18];
  const float* W_hn = (const float*)d_in[19];
  const float* b_hn = (const float*)d_in[20];
  const float* W_hk = (const float*)d_in[21];
  const float* b_hk = (const float*)d_in[22];
  const float* W_hv = (const float*)d_in[23];
  const float* b_hv = (const float*)d_in[24];
  const float* W_mk = (const float*)d_in[25];
  const float* b_mk = (const float*)d_in[26];
  const float* W_mv = (const float*)d_in[27];
  const float* b_mv = (const float*)d_in[28];
  float* out = (float*)d_out;

  char* wsp = (char*)d_ws;
  size_t off = 0;
  auto alloc = [&](size_t bytes) -> void* {
    void* pp = wsp + off;
    off = (off + bytes + 255) & ~(size_t)255;
    return pp;
  };
  unsigned* W4g    = (unsigned*)alloc((size_t)131072*4);
  unsigned* W4nkv  = (unsigned*)alloc((size_t)98304*4);
  unsigned* W4ph   = (unsigned*)alloc((size_t)98304*4);
  unsigned* WctP45 = (unsigned*)alloc((size_t)65536*4);
  unsigned* W4m0   = (unsigned*)alloc((size_t)4096*4);
  unsigned* W4qm   = (unsigned*)alloc((size_t)12288*4);
  unsigned* W4da   = (unsigned*)alloc((size_t)491520*4);
  unsigned* W4db   = (unsigned*)alloc((size_t)16384*4);
  unsigned* WgP    = (unsigned*)alloc((size_t)128*4);
  float* prehg     = (float*)alloc((size_t)29*B_*1024*4);
  unsigned* hNb    = (unsigned*)alloc((size_t)29*B_*128*4);
  unsigned* hNbT   = (unsigned*)alloc((size_t)29*B_*128*4);
  float* gt_all    = (float*)alloc((size_t)29*B_*4);
  float2* pmps     = (float2*)alloc((size_t)NG*512*8);
  float* loss_part = (float*)alloc(29*4);

  k_prep<<<744, 256, 131072, stream>>>(W_ct, W_hh, W_n, W_k, W_v,
      W_hn, W_hk, W_hv, W_mk, W_mv, W_g,
      W4g, W4nkv, W4ph, WctP45, W4m0, W4qm, W4da, W4db, WgP,
      sentence, emb, W_ih, b_ih, b_hh, prehg);

  LoopP P;
  P.sentence = sentence; P.keywords = keywords; P.categories = categories; P.memsz = memsz;
  P.emb = emb;
  P.W4g = W4g; P.W4nkv = W4nkv; P.W4ph = W4ph; P.WctP45 = WctP45;
  P.W4m0 = W4m0; P.W4qm = W4qm; P.W4da = W4da; P.W4db = W4db; P.WgP = WgP;
  P.prehg = prehg;
  P.b_ct = b_ct; P.b_hn = b_hn; P.b_hk = b_hk; P.b_hv = b_hv;
  P.b_mk = b_mk; P.b_mv = b_mv; P.b_g = b_g;
  P.hNb = hNb; P.hNbT = hNbT; P.gt_all = gt_all; P.outg = out + 1;

  k_loop<<<B_, 1024, 87812, stream>>>(P);
  k_vocab<<<NCHK, 256, 32768, stream>>>(hNbT, W_nv, b_nv, pmps);
  k_combine<<<29, 128, 0, stream>>>(pmps, hNb, W_nv, b_nv, gt_all, sentence, loss_part);
  k_fin<<<1, 64, 0, stream>>>(loss_part, out);
}